// Round 2
// baseline (17351.709 us; speedup 1.0000x reference)
//
#include <hip/hip_runtime.h>
#include <hip/hip_bf16.h>

typedef __hip_bfloat16 bf16;
typedef unsigned long long u64;
typedef unsigned int u32;
typedef unsigned short u16;
using short8 = __attribute__((ext_vector_type(8))) short;   // 8 bf16 MFMA A/B frag
using f32x4  = __attribute__((ext_vector_type(4))) float;   // MFMA C/D frag

#define T_STEPS 2048
#define IDIM    256
#define HDIM    512
#define NB0     32
#define NBLK    64
#define R0      8                 // h0 ring slots
#define HWW     8192              // u32 words per h buffer: [16 batch-pairs][512 units]
#define LROW    528               // LDS row stride (bf16 elems); 1056B == 8 dw mod 32

__device__ __forceinline__ float sigm(float x) { return 1.0f / (1.0f + __expf(-x)); }
__device__ __forceinline__ float tanh_f(float x) {
  x = fminf(fmaxf(x, -15.f), 15.f);
  float e = __expf(2.f * x);
  return (e - 1.f) / (e + 1.f);
}
__device__ __forceinline__ u16 bfbits(float f) {
  bf16 b = __float2bfloat16(f); u16 s; __builtin_memcpy(&s, &b, 2); return s;
}
__device__ __forceinline__ short8 cvt8(const float* __restrict__ p) {
  float4 lo = *(const float4*)(const void*)p;
  float4 hi = *(const float4*)(const void*)(p + 4);
  short8 r;
  r[0] = (short)bfbits(lo.x); r[1] = (short)bfbits(lo.y); r[2] = (short)bfbits(lo.z); r[3] = (short)bfbits(lo.w);
  r[4] = (short)bfbits(hi.x); r[5] = (short)bfbits(hi.y); r[6] = (short)bfbits(hi.z); r[7] = (short)bfbits(hi.w);
  return r;
}

// LLC-coherent (L1/L2-bypassing) accesses: agent-scope atomics.
__device__ __forceinline__ u64 ldg8(const u64* p) {
  return __hip_atomic_load(p, __ATOMIC_RELAXED, __HIP_MEMORY_SCOPE_AGENT);
}
__device__ __forceinline__ u32 ldg4(const u32* p) {
  return __hip_atomic_load(p, __ATOMIC_RELAXED, __HIP_MEMORY_SCOPE_AGENT);
}
__device__ __forceinline__ void stg4(u32* p, u32 v) {
  __hip_atomic_store(p, v, __ATOMIC_RELAXED, __HIP_MEMORY_SCOPE_AGENT);
}
// Per-wave release: s_waitcnt vmcnt(0)/lgkmcnt(0) is WAVE-wide, so lane 0's
// release store orders all 64 lanes' preceding data stores AND LDS reads.
__device__ __forceinline__ void stg_rel(u32* p, u32 v) {
  __hip_atomic_store(p, v, __ATOMIC_RELEASE, __HIP_MEMORY_SCOPE_AGENT);
}

__device__ __forceinline__ int wave_min_i(int v) {
#pragma unroll
  for (int off = 32; off > 0; off >>= 1) {
    int o = __shfl_xor(v, off, 64);
    v = v < o ? v : o;
  }
  return v;
}

// Spin until min over 128 per-wave flags >= target. One cache-line pair per pass.
__device__ __forceinline__ void wait_flags(const u32* __restrict__ f, u32 target, int lane) {
  for (;;) {
    u32 a = ldg4(f + lane);
    u32 b = ldg4(f + 64 + lane);
    u32 mv = a < b ? a : b;
    if ((u32)wave_min_i((int)mv) >= target) return;
  }
}

#define ACQ_FENCE() __builtin_amdgcn_fence(__ATOMIC_ACQUIRE, "agent")

// Single-pass stage of one 32KB h buffer (u32 word w: lo16 = h[w>>9][w&511],
// hi16 = h[(w>>9)+16][w&511]) into LDS [32][LROW] bf16. 256 thr x 16 u64 chunks.
__device__ __forceinline__ void stage_data(const u32* __restrict__ src, bf16* dst, int tid) {
  const u64* s = (const u64*)(const void*)src;
  u64 v[16];
#pragma unroll
  for (int i = 0; i < 16; i++) v[i] = ldg8(s + tid + i * 256);
  const int col = tid * 2;
#pragma unroll
  for (int i = 0; i < 16; i++) {
    u32 lo = (u32)v[i], hi = (u32)(v[i] >> 32);
    *(u32*)(void*)(dst + i * LROW + col)        = (lo & 0xffffu) | (hi << 16);
    *(u32*)(void*)(dst + (i + 16) * LROW + col) = (lo >> 16) | (hi & 0xffff0000u);
  }
}

#define MFMA(a, b, c) __builtin_amdgcn_mfma_f32_16x16x32_bf16((a), (b), (c), 0, 0, 0)

__global__ void __launch_bounds__(256, 1) lstm_persistent(
    const float* __restrict__ x,
    const float* __restrict__ Wih0, const float* __restrict__ Whh0,
    const float* __restrict__ bih0, const float* __restrict__ bhh0,
    const float* __restrict__ Wih1, const float* __restrict__ Whh1,
    const float* __restrict__ bih1, const float* __restrict__ bhh1,
    const float* __restrict__ fcw, const float* __restrict__ fcb,
    float* __restrict__ out,
    u32* __restrict__ prog,        // 32 x 128B l1 progress lines
    u32* __restrict__ flags0,      // 128 per-wave L0 completion flags
    u32* __restrict__ flags1,      // 128 per-wave L1 completion flags
    u32* __restrict__ h0ring,      // R0 x HWW packed bf16-pair words
    u32* __restrict__ h1ring) {    // 2  x HWW
  __shared__ __align__(16) bf16 lds_h0[32 * LROW];
  __shared__ __align__(16) bf16 lds_h1[32 * LROW];

  const int tid  = threadIdx.x;
  const int w    = tid >> 6, lane = tid & 63;
  const int q    = lane >> 4, m = lane & 15, q8 = q * 8;
  const int bx   = (int)blockIdx.x;
  const bool l0  = (bx < NB0);
  const int blk  = l0 ? bx : bx - NB0;
  const int jb   = blk * 16 + w * 4;
  const int unit = jb + (m >> 2), gate = m & 3;
  const int wrow = gate * HDIM + unit;
  const int ju   = jb + q;
  const int fidx = blk * 4 + w;
  const f32x4 zero = {0.f, 0.f, 0.f, 0.f};

  // ---- Preload weights (f32 -> bf16 A-frags) into VGPRs ----
  short8 A[32];
  f32x4 bias;
  if (l0) {
#pragma unroll
    for (int kc = 0; kc < 8; kc++)  A[kc]      = cvt8(Wih0 + wrow * IDIM + kc * 32 + q8);
#pragma unroll
    for (int kc = 0; kc < 16; kc++) A[8 + kc]  = cvt8(Whh0 + wrow * HDIM + kc * 32 + q8);
#pragma unroll
    for (int r = 0; r < 4; r++)
      bias[r] = bih0[r * HDIM + ju] + bhh0[r * HDIM + ju];
  } else {
#pragma unroll
    for (int kc = 0; kc < 16; kc++) A[kc]      = cvt8(Wih1 + wrow * HDIM + kc * 32 + q8);
#pragma unroll
    for (int kc = 0; kc < 16; kc++) A[16 + kc] = cvt8(Whh1 + wrow * HDIM + kc * 32 + q8);
#pragma unroll
    for (int r = 0; r < 4; r++)
      bias[r] = bih1[r * HDIM + ju] + bhh1[r * HDIM + ju];
  }

  float c_a = 0.f, c_b = 0.f;

  if (l0) {
    // prefetch xg[0]
    f32x4 an0 = bias, an1 = bias;
    {
      const float* xa = x + (size_t)m * (T_STEPS * IDIM) + q8;
      const float* xb = xa + (size_t)16 * (T_STEPS * IDIM);
#pragma unroll
      for (int kc = 0; kc < 8; kc++) {
        an0 = MFMA(A[kc], cvt8(xa + kc * 32), an0);
        an1 = MFMA(A[kc], cvt8(xb + kc * 32), an1);
      }
    }
    int est = 0;   // cached min l1 progress
    for (int p = 0; p < T_STEPS; ++p) {
      f32x4 a0 = an0, a1 = an1;                       // bias + Wih0 x[p]
      if (p > 0) {
        wait_flags(flags0, (u32)p, lane);             // h0[p-1] complete everywhere
        ACQ_FENCE();
        stage_data(h0ring + ((p - 1) & (R0 - 1)) * HWW, lds_h0, tid);
        __syncthreads();
        f32x4 b0 = zero, b1 = zero;                   // split chains: 4 deep-8 pipes
#pragma unroll
        for (int kc = 0; kc < 8; kc++) {
          short8 r0 = *(const short8*)(const void*)(lds_h0 + m * LROW + kc * 32 + q8);
          short8 r1 = *(const short8*)(const void*)(lds_h0 + (m + 16) * LROW + kc * 32 + q8);
          a0 = MFMA(A[8 + kc], r0, a0);
          a1 = MFMA(A[8 + kc], r1, a1);
          short8 s0 = *(const short8*)(const void*)(lds_h0 + m * LROW + (kc + 8) * 32 + q8);
          short8 s1 = *(const short8*)(const void*)(lds_h0 + (m + 16) * LROW + (kc + 8) * 32 + q8);
          b0 = MFMA(A[16 + kc], s0, b0);
          b1 = MFMA(A[16 + kc], s1, b1);
        }
        a0 = a0 + b0; a1 = a1 + b1;
      }
      float ia = sigm(a0[0]), fa = sigm(a0[1]), ga = tanh_f(a0[2]), oa = sigm(a0[3]);
      c_a = fa * c_a + ia * ga;
      float ib = sigm(a1[0]), fb = sigm(a1[1]), gb = tanh_f(a1[2]), ob = sigm(a1[3]);
      c_b = fb * c_b + ib * gb;
      u32 pack = (u32)bfbits(oa * tanh_f(c_a)) | ((u32)bfbits(ob * tanh_f(c_b)) << 16);

      // flow control: slot p%R0 currently holds h0[p-R0] (readers: l1 step p-R0 -> prog p-R0+1)
      if (p >= R0) {
        int needed = p - R0 + 1;
        if (est < needed) {
          int mn;
          do {
            u32 pr = ldg4(prog + (lane & 31) * 32);
            mn = wave_min_i((int)pr);
          } while (mn < needed);
          est = mn;
        }
      }
      stg4(h0ring + (p & (R0 - 1)) * HWW + (m << 9) + ju, pack);
      if (lane == 0) stg_rel(flags0 + fidx, (u32)(p + 1));   // wave-wide vmcnt drain

      if (p + 1 < T_STEPS) {                          // prefetch xg[p+1] (off critical path)
        an0 = bias; an1 = bias;
        const float* xa = x + (size_t)m * (T_STEPS * IDIM) + (size_t)(p + 1) * IDIM + q8;
        const float* xb = xa + (size_t)16 * (T_STEPS * IDIM);
#pragma unroll
        for (int kc = 0; kc < 8; kc++) {
          an0 = MFMA(A[kc], cvt8(xa + kc * 32), an0);
          an1 = MFMA(A[kc], cvt8(xb + kc * 32), an1);
        }
      }
      // No trailing barrier: next iter's wait_flags >= p+1 includes OWN waves,
      // which release only after their lds_h0 reads (MFMAs) completed.
    }

    // ---- FC epilogue: blocks 0..15 wait for all L1 waves then read h1[T-1] ----
    if (bx < 16) {
      wait_flags(flags1, (u32)T_STEPS, lane);
      ACQ_FENCE();
      stage_data(h1ring + ((T_STEPS - 1) & 1) * HWW, lds_h0, tid);
      __syncthreads();
      if (w == 0) {
        const int obase = bx * 16;
        f32x4 a0, a1;
#pragma unroll
        for (int r = 0; r < 4; r++) {
          float bb = fcb[obase + 4 * q + r];
          a0[r] = bb; a1[r] = bb;
        }
        const float* Ar = fcw + (size_t)(obase + m) * HDIM + q8;
#pragma unroll
        for (int kc = 0; kc < 16; kc++) {
          short8 af = cvt8(Ar + kc * 32);
          short8 b0 = *(const short8*)(const void*)(lds_h0 + m * LROW + kc * 32 + q8);
          short8 b1 = *(const short8*)(const void*)(lds_h0 + (m + 16) * LROW + kc * 32 + q8);
          a0 = MFMA(af, b0, a0);
          a1 = MFMA(af, b1, a1);
        }
#pragma unroll
        for (int r = 0; r < 4; r++) {
          out[m * 256 + obase + 4 * q + r]        = a0[r];
          out[(m + 16) * 256 + obase + 4 * q + r] = a1[r];
        }
      }
    }
  } else {
    // ---- layer 1: stage h0 + Wih1 part first (h0 ready early), poll h1 late ----
    for (int p = 0; p < T_STEPS; ++p) {
      wait_flags(flags0, (u32)(p + 1), lane);         // h0[p] (L0 runs up to 8 ahead)
      ACQ_FENCE();
      stage_data(h0ring + (p & (R0 - 1)) * HWW, lds_h0, tid);
      __syncthreads();
      if (tid == 0) stg4(prog + blk * 32, (u32)(p + 1));   // done reading h0[p]

      f32x4 a0 = bias, a1 = bias, p0 = zero, p1 = zero;
#pragma unroll
      for (int kc = 0; kc < 8; kc++) {
        short8 r0 = *(const short8*)(const void*)(lds_h0 + m * LROW + kc * 32 + q8);
        short8 r1 = *(const short8*)(const void*)(lds_h0 + (m + 16) * LROW + kc * 32 + q8);
        a0 = MFMA(A[kc], r0, a0);
        a1 = MFMA(A[kc], r1, a1);
        short8 s0 = *(const short8*)(const void*)(lds_h0 + m * LROW + (kc + 8) * 32 + q8);
        short8 s1 = *(const short8*)(const void*)(lds_h0 + (m + 16) * LROW + (kc + 8) * 32 + q8);
        p0 = MFMA(A[8 + kc], s0, p0);
        p1 = MFMA(A[8 + kc], s1, p1);
      }
      if (p >= 1) {
        wait_flags(flags1, (u32)p, lane);             // h1[p-1]
        ACQ_FENCE();
        stage_data(h1ring + ((p - 1) & 1) * HWW, lds_h1, tid);
        __syncthreads();
#pragma unroll
        for (int kc = 0; kc < 8; kc++) {
          short8 r0 = *(const short8*)(const void*)(lds_h1 + m * LROW + kc * 32 + q8);
          short8 r1 = *(const short8*)(const void*)(lds_h1 + (m + 16) * LROW + kc * 32 + q8);
          a0 = MFMA(A[16 + kc], r0, a0);
          a1 = MFMA(A[16 + kc], r1, a1);
          short8 s0 = *(const short8*)(const void*)(lds_h1 + m * LROW + (kc + 8) * 32 + q8);
          short8 s1 = *(const short8*)(const void*)(lds_h1 + (m + 16) * LROW + (kc + 8) * 32 + q8);
          p0 = MFMA(A[24 + kc], s0, p0);
          p1 = MFMA(A[24 + kc], s1, p1);
        }
      }
      a0 = a0 + p0; a1 = a1 + p1;
      float ia = sigm(a0[0]), fa = sigm(a0[1]), ga = tanh_f(a0[2]), oa = sigm(a0[3]);
      c_a = fa * c_a + ia * ga;
      float ib = sigm(a1[0]), fb = sigm(a1[1]), gb = tanh_f(a1[2]), ob = sigm(a1[3]);
      c_b = fb * c_b + ib * gb;
      u32 pack = (u32)bfbits(oa * tanh_f(c_a)) | ((u32)bfbits(ob * tanh_f(c_b)) << 16);
      stg4(h1ring + (p & 1) * HWW + (m << 9) + ju, pack);
      if (lane == 0) stg_rel(flags1 + fidx, (u32)(p + 1));
      __syncthreads();   // lds_h0/h1 reads done before next iter's staging overwrites
    }
  }
}

extern "C" void kernel_launch(void* const* d_in, const int* in_sizes, int n_in,
                              void* d_out, int out_size, void* d_ws, size_t ws_size,
                              hipStream_t stream) {
  const float* x    = (const float*)d_in[0];
  const float* Wih0 = (const float*)d_in[1];
  const float* Whh0 = (const float*)d_in[2];
  const float* bih0 = (const float*)d_in[3];
  const float* bhh0 = (const float*)d_in[4];
  const float* Wih1 = (const float*)d_in[5];
  const float* Whh1 = (const float*)d_in[6];
  const float* bih1 = (const float*)d_in[7];
  const float* bhh1 = (const float*)d_in[8];
  const float* fcw  = (const float*)d_in[9];
  const float* fcb  = (const float*)d_in[10];

  // ws: [0,4K) l1 progress lines; [4K,4K+512) flags0; [4.5K,5K) flags1;
  // [8K, 8K+256K) h0 ring; then 64K h1 ring.
  // Ring data needs no init: validity is gated purely by the release flags,
  // which (with prog) live in the zeroed first 8KB.
  u32* prog   = (u32*)d_ws;
  u32* flags0 = (u32*)((char*)d_ws + 4096);
  u32* flags1 = (u32*)((char*)d_ws + 4096 + 512);
  u32* h0ring = (u32*)((char*)d_ws + 8192);
  u32* h1ring = (u32*)((char*)d_ws + 8192 + (size_t)R0 * HWW * sizeof(u32));

  hipMemsetAsync(d_ws, 0, 8192, stream);   // progress + flags start at 0

  hipLaunchKernelGGL(lstm_persistent, dim3(NBLK), dim3(256), 0, stream,
                     x, Wih0, Whh0, bih0, bhh0, Wih1, Whh1, bih1, bhh1, fcw, fcb,
                     (float*)d_out, prog, flags0, flags1, h0ring, h1ring);
}

// Round 3
// 14516.774 us; speedup vs baseline: 1.1953x; 1.1953x over previous
//
#include <hip/hip_runtime.h>
#include <hip/hip_bf16.h>

typedef __hip_bfloat16 bf16;
typedef unsigned long long u64;
typedef unsigned int u32;
typedef unsigned short u16;
using short8 = __attribute__((ext_vector_type(8))) short;   // 8 bf16 MFMA A/B frag
using f32x4  = __attribute__((ext_vector_type(4))) float;   // MFMA C/D frag

#define T_STEPS 2048
#define IDIM    256
#define HDIM    512
#define NB0     32
#define NBLK    64
#define R0      16                // h0 ring slots (deep slack decouples L0/L1 phases)
#define HWW     8192              // u32 words per h buffer: [16 batch-pairs][512 units]
#define LROW    528               // LDS row stride (bf16 elems); 1056B == 8 dw mod 32

__device__ __forceinline__ float sigm(float x) { return 1.0f / (1.0f + __expf(-x)); }
__device__ __forceinline__ float tanh_f(float x) {
  x = fminf(fmaxf(x, -15.f), 15.f);
  float e = __expf(2.f * x);
  return (e - 1.f) / (e + 1.f);
}
__device__ __forceinline__ u16 bfbits(float f) {
  bf16 b = __float2bfloat16(f); u16 s; __builtin_memcpy(&s, &b, 2); return s;
}
__device__ __forceinline__ short8 cvt8(const float* __restrict__ p) {
  float4 lo = *(const float4*)(const void*)p;
  float4 hi = *(const float4*)(const void*)(p + 4);
  short8 r;
  r[0] = (short)bfbits(lo.x); r[1] = (short)bfbits(lo.y); r[2] = (short)bfbits(lo.z); r[3] = (short)bfbits(lo.w);
  r[4] = (short)bfbits(hi.x); r[5] = (short)bfbits(hi.y); r[6] = (short)bfbits(hi.z); r[7] = (short)bfbits(hi.w);
  return r;
}

// LLC-coherent (L1/L2-bypassing) accesses: agent-scope atomics.
__device__ __forceinline__ u64 ldg8(const u64* p) {
  return __hip_atomic_load(p, __ATOMIC_RELAXED, __HIP_MEMORY_SCOPE_AGENT);
}
__device__ __forceinline__ u32 ldg4(const u32* p) {
  return __hip_atomic_load(p, __ATOMIC_RELAXED, __HIP_MEMORY_SCOPE_AGENT);
}
__device__ __forceinline__ void stg4(u32* p, u32 v) {
  __hip_atomic_store(p, v, __ATOMIC_RELAXED, __HIP_MEMORY_SCOPE_AGENT);
}
__device__ __forceinline__ void stg_rel(u32* p, u32 v) {
  __hip_atomic_store(p, v, __ATOMIC_RELEASE, __HIP_MEMORY_SCOPE_AGENT);
}

// Per-wave store drain: sc1 stores are globally visible (at LLC) once vmcnt==0.
#define DRAIN() asm volatile("s_waitcnt vmcnt(0)" ::: "memory")

__device__ __forceinline__ int wave_min_i(int v) {
#pragma unroll
  for (int off = 32; off > 0; off >>= 1) {
    int o = __shfl_xor(v, off, 64);
    v = v < o ? v : o;
  }
  return v;
}

// L0 step-p gate (single combined wait): lanes 0-31 check own-layer flags
// (need >= p: everyone finished p-1); lanes 32-63 check L1 flags + (R0-1)
// (ring slot p&(R0-1) holds h0[p-R0], freed once L1 finished step p-R0+1... => f1 >= p-R0+1).
__device__ __forceinline__ void wait_l0(const u32* __restrict__ f0,
                                        const u32* __restrict__ f1, int p, int lane) {
  for (;;) {
    int v = (lane < 32) ? (int)ldg4(f0 + lane)
                        : (int)ldg4(f1 + (lane - 32)) + (R0 - 1);
    if (wave_min_i(v) >= p) return;
  }
}
// L1 step-p gate: need f0 >= p+1 (h0[p] published) and f1 >= p (h1[p-1] published,
// and h1 slot p&1 free: all L1 finished step p-1 means they consumed h1[p-2] from slot p&1).
__device__ __forceinline__ void wait_l1(const u32* __restrict__ f0,
                                        const u32* __restrict__ f1, int p, int lane) {
  for (;;) {
    int v = (lane < 32) ? (int)ldg4(f0 + lane) - 1
                        : (int)ldg4(f1 + (lane - 32));
    if (wave_min_i(v) >= p) return;
  }
}

// Single-pass stage of one 32KB h buffer (u32 word w: lo16 = h[w>>9][w&511],
// hi16 = h[(w>>9)+16][w&511]) into LDS [32][LROW] bf16. 256 thr x 16 u64 chunks.
__device__ __forceinline__ void stage_data(const u32* __restrict__ src, bf16* dst, int tid) {
  const u64* s = (const u64*)(const void*)src;
  u64 v[16];
#pragma unroll
  for (int i = 0; i < 16; i++) v[i] = ldg8(s + tid + i * 256);
  const int col = tid * 2;
#pragma unroll
  for (int i = 0; i < 16; i++) {
    u32 lo = (u32)v[i], hi = (u32)(v[i] >> 32);
    *(u32*)(void*)(dst + i * LROW + col)        = (lo & 0xffffu) | (hi << 16);
    *(u32*)(void*)(dst + (i + 16) * LROW + col) = (lo >> 16) | (hi & 0xffff0000u);
  }
}

// Stage two buffers in one burst: all 32 loads in flight together.
__device__ __forceinline__ void stage2p(const u32* __restrict__ s0p, bf16* d0,
                                        const u32* __restrict__ s1p, bf16* d1, int tid) {
  const u64* s0 = (const u64*)(const void*)s0p;
  const u64* s1 = (const u64*)(const void*)s1p;
  u64 v0[16], v1[16];
#pragma unroll
  for (int i = 0; i < 16; i++) v0[i] = ldg8(s0 + tid + i * 256);
#pragma unroll
  for (int i = 0; i < 16; i++) v1[i] = ldg8(s1 + tid + i * 256);
  const int col = tid * 2;
#pragma unroll
  for (int i = 0; i < 16; i++) {
    u32 lo = (u32)v0[i], hi = (u32)(v0[i] >> 32);
    *(u32*)(void*)(d0 + i * LROW + col)        = (lo & 0xffffu) | (hi << 16);
    *(u32*)(void*)(d0 + (i + 16) * LROW + col) = (lo >> 16) | (hi & 0xffff0000u);
  }
#pragma unroll
  for (int i = 0; i < 16; i++) {
    u32 lo = (u32)v1[i], hi = (u32)(v1[i] >> 32);
    *(u32*)(void*)(d1 + i * LROW + col)        = (lo & 0xffffu) | (hi << 16);
    *(u32*)(void*)(d1 + (i + 16) * LROW + col) = (lo >> 16) | (hi & 0xffff0000u);
  }
}

#define MFMA(a, b, c) __builtin_amdgcn_mfma_f32_16x16x32_bf16((a), (b), (c), 0, 0, 0)

__global__ void __launch_bounds__(256, 1) lstm_persistent(
    const float* __restrict__ x,
    const float* __restrict__ Wih0, const float* __restrict__ Whh0,
    const float* __restrict__ bih0, const float* __restrict__ bhh0,
    const float* __restrict__ Wih1, const float* __restrict__ Whh1,
    const float* __restrict__ bih1, const float* __restrict__ bhh1,
    const float* __restrict__ fcw, const float* __restrict__ fcb,
    float* __restrict__ out,
    u32* __restrict__ flags0,      // 32 per-BLOCK L0 step-complete flags
    u32* __restrict__ flags1,      // 32 per-BLOCK L1 step-complete flags (doubles as prog)
    u32* __restrict__ h0ring,      // R0 x HWW packed bf16-pair words
    u32* __restrict__ h1ring) {    // 2  x HWW
  __shared__ __align__(16) bf16 lds_h0[32 * LROW];
  __shared__ __align__(16) bf16 lds_h1[32 * LROW];

  const int tid  = threadIdx.x;
  const int w    = tid >> 6, lane = tid & 63;
  const int q    = lane >> 4, m = lane & 15, q8 = q * 8;
  const int bx   = (int)blockIdx.x;
  const bool l0  = (bx < NB0);
  const int blk  = l0 ? bx : bx - NB0;
  const int jb   = blk * 16 + w * 4;
  const int unit = jb + (m >> 2), gate = m & 3;
  const int wrow = gate * HDIM + unit;
  const int ju   = jb + q;
  const f32x4 zero = {0.f, 0.f, 0.f, 0.f};

  // ---- Preload weights (f32 -> bf16 A-frags) into VGPRs ----
  short8 A[32];
  f32x4 bias;
  if (l0) {
#pragma unroll
    for (int kc = 0; kc < 8; kc++)  A[kc]      = cvt8(Wih0 + wrow * IDIM + kc * 32 + q8);
#pragma unroll
    for (int kc = 0; kc < 16; kc++) A[8 + kc]  = cvt8(Whh0 + wrow * HDIM + kc * 32 + q8);
#pragma unroll
    for (int r = 0; r < 4; r++)
      bias[r] = bih0[r * HDIM + ju] + bhh0[r * HDIM + ju];
  } else {
#pragma unroll
    for (int kc = 0; kc < 16; kc++) A[kc]      = cvt8(Wih1 + wrow * HDIM + kc * 32 + q8);
#pragma unroll
    for (int kc = 0; kc < 16; kc++) A[16 + kc] = cvt8(Whh1 + wrow * HDIM + kc * 32 + q8);
#pragma unroll
    for (int r = 0; r < 4; r++)
      bias[r] = bih1[r * HDIM + ju] + bhh1[r * HDIM + ju];
  }

  float c_a = 0.f, c_b = 0.f;

  if (l0) {
    // prefetch xg[0]
    f32x4 an0 = bias, an1 = bias;
    {
      const float* xa = x + (size_t)m * (T_STEPS * IDIM) + q8;
      const float* xb = xa + (size_t)16 * (T_STEPS * IDIM);
#pragma unroll
      for (int kc = 0; kc < 8; kc++) {
        an0 = MFMA(A[kc], cvt8(xa + kc * 32), an0);
        an1 = MFMA(A[kc], cvt8(xb + kc * 32), an1);
      }
    }
    for (int p = 0; p < T_STEPS; ++p) {
      f32x4 a0 = an0, a1 = an1;                       // bias + Wih0 x[p]
      if (p > 0) {
        wait_l0(flags0, flags1, p, lane);             // h0[p-1] ready AND ring slot free
        stage_data(h0ring + ((p - 1) & (R0 - 1)) * HWW, lds_h0, tid);
        __syncthreads();
        f32x4 b0 = zero, b1 = zero;                   // split chains: 4 deep-8 pipes
#pragma unroll
        for (int kc = 0; kc < 8; kc++) {
          short8 r0 = *(const short8*)(const void*)(lds_h0 + m * LROW + kc * 32 + q8);
          short8 r1 = *(const short8*)(const void*)(lds_h0 + (m + 16) * LROW + kc * 32 + q8);
          a0 = MFMA(A[8 + kc], r0, a0);
          a1 = MFMA(A[8 + kc], r1, a1);
          short8 s0 = *(const short8*)(const void*)(lds_h0 + m * LROW + (kc + 8) * 32 + q8);
          short8 s1 = *(const short8*)(const void*)(lds_h0 + (m + 16) * LROW + (kc + 8) * 32 + q8);
          b0 = MFMA(A[16 + kc], s0, b0);
          b1 = MFMA(A[16 + kc], s1, b1);
        }
        a0 = a0 + b0; a1 = a1 + b1;
      }
      float ia = sigm(a0[0]), fa = sigm(a0[1]), ga = tanh_f(a0[2]), oa = sigm(a0[3]);
      c_a = fa * c_a + ia * ga;
      float ib = sigm(a1[0]), fb = sigm(a1[1]), gb = tanh_f(a1[2]), ob = sigm(a1[3]);
      c_b = fb * c_b + ib * gb;
      u32 pack = (u32)bfbits(oa * tanh_f(c_a)) | ((u32)bfbits(ob * tanh_f(c_b)) << 16);

      stg4(h0ring + (p & (R0 - 1)) * HWW + (m << 9) + ju, pack);
      DRAIN();                                        // this wave's stores at LLC
      __syncthreads();                                // all 4 waves drained
      if (tid == 0) stg_rel(flags0 + bx, (u32)(p + 1));

      if (p + 1 < T_STEPS) {                          // prefetch xg[p+1] (off critical path)
        an0 = bias; an1 = bias;
        const float* xa = x + (size_t)m * (T_STEPS * IDIM) + (size_t)(p + 1) * IDIM + q8;
        const float* xb = xa + (size_t)16 * (T_STEPS * IDIM);
#pragma unroll
        for (int kc = 0; kc < 8; kc++) {
          an0 = MFMA(A[kc], cvt8(xa + kc * 32), an0);
          an1 = MFMA(A[kc], cvt8(xb + kc * 32), an1);
        }
      }
      // Safe to re-stage lds_h0 next iter: wait_l0(p+1) needs own flag >= p+1,
      // released only after the post-compute barrier (MFMA ds_reads data-dep done).
    }

    // ---- FC epilogue: blocks 0..15 wait for all L1 blocks then read h1[T-1] ----
    if (bx < 16) {
      for (;;) {
        int v = (int)ldg4(flags1 + (lane & 31));
        if (wave_min_i(v) >= T_STEPS) break;
      }
      stage_data(h1ring + ((T_STEPS - 1) & 1) * HWW, lds_h0, tid);
      __syncthreads();
      if (w == 0) {
        const int obase = bx * 16;
        f32x4 a0, a1;
#pragma unroll
        for (int r = 0; r < 4; r++) {
          float bb = fcb[obase + 4 * q + r];
          a0[r] = bb; a1[r] = bb;
        }
        const float* Ar = fcw + (size_t)(obase + m) * HDIM + q8;
#pragma unroll
        for (int kc = 0; kc < 16; kc++) {
          short8 af = cvt8(Ar + kc * 32);
          short8 b0 = *(const short8*)(const void*)(lds_h0 + m * LROW + kc * 32 + q8);
          short8 b1 = *(const short8*)(const void*)(lds_h0 + (m + 16) * LROW + kc * 32 + q8);
          a0 = MFMA(af, b0, a0);
          a1 = MFMA(af, b1, a1);
        }
#pragma unroll
        for (int r = 0; r < 4; r++) {
          out[m * 256 + obase + 4 * q + r]        = a0[r];
          out[(m + 16) * 256 + obase + 4 * q + r] = a1[r];
        }
      }
    }
  } else {
    // ---- layer 1: ONE combined wait, ONE merged stage, straight-line compute ----
    for (int p = 0; p < T_STEPS; ++p) {
      wait_l1(flags0, flags1, p, lane);               // h0[p] AND h1[p-1] both published
      if (p == 0) {
        stage_data(h0ring + 0 * HWW, lds_h0, tid);
      } else {
        stage2p(h0ring + (p & (R0 - 1)) * HWW, lds_h0,
                h1ring + ((p - 1) & 1) * HWW, lds_h1, tid);
      }
      __syncthreads();

      f32x4 a0 = bias, a1 = bias, p0 = zero, p1 = zero;
#pragma unroll
      for (int kc = 0; kc < 8; kc++) {
        short8 r0 = *(const short8*)(const void*)(lds_h0 + m * LROW + kc * 32 + q8);
        short8 r1 = *(const short8*)(const void*)(lds_h0 + (m + 16) * LROW + kc * 32 + q8);
        a0 = MFMA(A[kc], r0, a0);
        a1 = MFMA(A[kc], r1, a1);
        short8 s0 = *(const short8*)(const void*)(lds_h0 + m * LROW + (kc + 8) * 32 + q8);
        short8 s1 = *(const short8*)(const void*)(lds_h0 + (m + 16) * LROW + (kc + 8) * 32 + q8);
        p0 = MFMA(A[8 + kc], s0, p0);
        p1 = MFMA(A[8 + kc], s1, p1);
      }
      if (p >= 1) {
#pragma unroll
        for (int kc = 0; kc < 8; kc++) {
          short8 r0 = *(const short8*)(const void*)(lds_h1 + m * LROW + kc * 32 + q8);
          short8 r1 = *(const short8*)(const void*)(lds_h1 + (m + 16) * LROW + kc * 32 + q8);
          a0 = MFMA(A[16 + kc], r0, a0);
          a1 = MFMA(A[16 + kc], r1, a1);
          short8 s0 = *(const short8*)(const void*)(lds_h1 + m * LROW + (kc + 8) * 32 + q8);
          short8 s1 = *(const short8*)(const void*)(lds_h1 + (m + 16) * LROW + (kc + 8) * 32 + q8);
          p0 = MFMA(A[24 + kc], s0, p0);
          p1 = MFMA(A[24 + kc], s1, p1);
        }
      }
      a0 = a0 + p0; a1 = a1 + p1;
      float ia = sigm(a0[0]), fa = sigm(a0[1]), ga = tanh_f(a0[2]), oa = sigm(a0[3]);
      c_a = fa * c_a + ia * ga;
      float ib = sigm(a1[0]), fb = sigm(a1[1]), gb = tanh_f(a1[2]), ob = sigm(a1[3]);
      c_b = fb * c_b + ib * gb;
      u32 pack = (u32)bfbits(oa * tanh_f(c_a)) | ((u32)bfbits(ob * tanh_f(c_b)) << 16);
      stg4(h1ring + (p & 1) * HWW + (m << 9) + ju, pack);
      DRAIN();
      __syncthreads();
      if (tid == 0) stg_rel(flags1 + blk, (u32)(p + 1));
      // Next iter's wait_l1(p+1) needs own flag >= p+1 (just released) -> own waves'
      // LDS reads are data-dep complete; safe to re-stage.
    }
  }
}

extern "C" void kernel_launch(void* const* d_in, const int* in_sizes, int n_in,
                              void* d_out, int out_size, void* d_ws, size_t ws_size,
                              hipStream_t stream) {
  const float* x    = (const float*)d_in[0];
  const float* Wih0 = (const float*)d_in[1];
  const float* Whh0 = (const float*)d_in[2];
  const float* bih0 = (const float*)d_in[3];
  const float* bhh0 = (const float*)d_in[4];
  const float* Wih1 = (const float*)d_in[5];
  const float* Whh1 = (const float*)d_in[6];
  const float* bih1 = (const float*)d_in[7];
  const float* bhh1 = (const float*)d_in[8];
  const float* fcw  = (const float*)d_in[9];
  const float* fcb  = (const float*)d_in[10];

  // ws: [0,128) flags0 (32 u32, one line); [128,256) flags1; rings at 8K.
  // Ring data needs no init: validity gated purely by the release flags.
  u32* flags0 = (u32*)d_ws;
  u32* flags1 = (u32*)((char*)d_ws + 128);
  u32* h0ring = (u32*)((char*)d_ws + 8192);
  u32* h1ring = (u32*)((char*)d_ws + 8192 + (size_t)R0 * HWW * sizeof(u32));

  hipMemsetAsync(d_ws, 0, 8192, stream);   // flags start at 0

  hipLaunchKernelGGL(lstm_persistent, dim3(NBLK), dim3(256), 0, stream,
                     x, Wih0, Whh0, bih0, bhh0, Wih1, Whh1, bih1, bhh1, fcw, fcb,
                     (float*)d_out, flags0, flags1, h0ring, h1ring);
}